// Round 4
// baseline (679.737 us; speedup 1.0000x reference)
//
#include <hip/hip_runtime.h>
#include <stdint.h>

// ---------------------------------------------------------------------------
// PDG2Seq_GCN: B=16, N=1024, C=O=64, D=10, CHEB_K=2 (K=5 stacked terms)
// Round 4: single mega-kernel (512 blocks x 256 thr, guaranteed co-resident
// via __launch_bounds__(256,2) + 32KB LDS => 2 blocks/CU) with homebrew
// grid barriers. Phases:
//   A: transpose_x (256 jobs) + transpose_wp (50 jobs)
//   B: hop1  X1 = A @ x          (barrier-free vmcnt-pipelined MFMA)
//   C: hop2  X2 = A @ X1 (reversed order, LLC-hot adj) + wgen (WT)
//   D: final out = Xg @ W_n + bias
// Barrier counter lives in d_ws (zeroed by captured hipMemsetAsync).
// ---------------------------------------------------------------------------

typedef __attribute__((ext_vector_type(4))) float f32x4;
typedef __attribute__((ext_vector_type(2))) float f32x2;
typedef __attribute__((ext_vector_type(8))) short s16x8;
typedef __attribute__((ext_vector_type(8))) __bf16 bf16x8;

__device__ __forceinline__ unsigned short f2bf(float f) {
  union { float f; uint32_t u; } v; v.f = f;
  uint32_t r = v.u + 0x7FFFu + ((v.u >> 16) & 1u);   // RNE
  return (unsigned short)(r >> 16);
}
__device__ __forceinline__ uint32_t pack2(float a, float b) {
  return (uint32_t)f2bf(a) | ((uint32_t)f2bf(b) << 16);
}

union FragU { s16x8 s; bf16x8 b; };

__device__ __forceinline__ void async_cp16(const void* g, void* l) {
  __builtin_amdgcn_global_load_lds(
      (const __attribute__((address_space(1))) void*)g,
      (__attribute__((address_space(3))) void*)l, 16, 0, 0);
}

// s_waitcnt with only vmcnt constrained (expcnt=7, lgkmcnt=15 -> no wait)
#define WAITVM(n)                                                         \
  __builtin_amdgcn_s_waitcnt(((n) & 15) | ((((n) >> 4) & 3) << 14) |      \
                             (7 << 4) | (15 << 8))

// Grid barrier: monotonic counter, all blocks co-resident by construction.
// Release: every wave drains+writes back (threadfence) before arrival.
// Acquire: invalidate after observing target.
__device__ __forceinline__ void gridbar(unsigned* cnt, unsigned target) {
  __threadfence();                 // all waves: vmcnt drain + L2 writeback
  __syncthreads();
  if (threadIdx.x == 0) {
    atomicAdd(cnt, 1u);
    while (atomicAdd(cnt, 0u) < target) __builtin_amdgcn_s_sleep(16);
  }
  __syncthreads();
  __threadfence();                 // acquire: invalidate stale lines
}

// ---------------------------------------------------------------------------
// hop body: out[64 rows][64] += A_rows @ X  over k=0..1023, MFMA bf16.
// Wave-private LDS A staging via global_load_lds, per-wave vmcnt sync,
// no block barrier in the K-loop. All pointers pre-offset to the slice.
// ---------------------------------------------------------------------------
__device__ __forceinline__ void hop_body(
    char* smem, const float* __restrict__ A,
    const unsigned short* __restrict__ XT, float* __restrict__ Xout,
    unsigned short* __restrict__ XTout, int write_xt, int rowbase) {
  const int tid = threadIdx.x;
  const int wave = tid >> 6, lane = tid & 63;
  const int l15 = lane & 15, q = lane >> 4;

  float* const Abase = (float*)smem + wave * 2048;   // 2 stages x 1024 f32

  const float* ag[4];
#pragma unroll
  for (int i = 0; i < 4; ++i) {
    const int wl = i * 4 + (lane >> 4);              // wave-local row 0..15
    const int ch = (lane & 15) ^ (wl & 7);           // swizzled 4-float chunk
    ag[i] = A + (size_t)(rowbase + wave * 16 + wl) * 1024 + ch * 4;
  }
  const unsigned short* bg[8];
#pragma unroll
  for (int t = 0; t < 4; ++t)
#pragma unroll
    for (int h = 0; h < 2; ++h)
      bg[t * 2 + h] = XT + (size_t)(t * 16 + l15) * 1024 + h * 32 + q * 8;

  f32x4 acc[4];
#pragma unroll
  for (int t = 0; t < 4; ++t) acc[t] = (f32x4){0.f, 0.f, 0.f, 0.f};

  s16x8 breg0[8], breg1[8];

  auto issueA = [&](int k0, int s) {
#pragma unroll
    for (int i = 0; i < 4; ++i)
      async_cp16(ag[i] + k0, Abase + s * 1024 + i * 256);
  };
  auto issueB = [&](int k0, s16x8 (&br)[8]) {
#pragma unroll
    for (int j = 0; j < 8; ++j) br[j] = *(const s16x8*)(bg[j] + k0);
  };
  auto compute = [&](int s, const s16x8 (&br)[8]) {
    const float* Ab = Abase + s * 1024;
    const int sw = l15 & 7;
#pragma unroll
    for (int h = 0; h < 2; ++h) {
      const int j0 = h * 8 + q * 2;
      f32x4 c0 = *(const f32x4*)(Ab + l15 * 64 + (j0 ^ sw) * 4);
      f32x4 c1 = *(const f32x4*)(Ab + l15 * 64 + ((j0 + 1) ^ sw) * 4);
      FragU af;
#pragma unroll
      for (int e = 0; e < 4; ++e) {
        af.s[e]     = (short)f2bf(c0[e]);
        af.s[e + 4] = (short)f2bf(c1[e]);
      }
#pragma unroll
      for (int t = 0; t < 4; ++t) {
        FragU bf; bf.s = br[t * 2 + h];
        acc[t] = __builtin_amdgcn_mfma_f32_16x16x32_bf16(af.b, bf.b, acc[t],
                                                         0, 0, 0);
      }
    }
  };

  issueA(0, 0);    issueB(0, breg0);
  issueA(64, 1);   issueB(64, breg1);
#pragma unroll 1
  for (int kt = 0; kt < 14; kt += 2) {
    WAITVM(12);
    compute(0, breg0);
    issueA((kt + 2) * 64, 0); issueB((kt + 2) * 64, breg0);
    WAITVM(12);
    compute(1, breg1);
    issueA((kt + 3) * 64, 1); issueB((kt + 3) * 64, breg1);
  }
  WAITVM(12);
  compute(0, breg0);
  WAITVM(0);
  compute(1, breg1);

  // Epilogue: transpose via LDS (reuse stage memory)
  __syncthreads();
  float (*tile)[65] = (float(*)[65])smem;
#pragma unroll
  for (int t = 0; t < 4; ++t)
#pragma unroll
    for (int rr = 0; rr < 4; ++rr)
      tile[wave * 16 + q * 4 + rr][t * 16 + l15] = acc[t][rr];
  __syncthreads();

  {
    const int row = tid >> 2;
    const int cb = (tid & 3) * 16;
    float* __restrict__ outp = Xout + (size_t)(rowbase + row) * 64 + cb;
#pragma unroll
    for (int u = 0; u < 4; ++u) {
      f32x4 v = { tile[row][cb + 4 * u], tile[row][cb + 4 * u + 1],
                  tile[row][cb + 4 * u + 2], tile[row][cb + 4 * u + 3] };
      *(f32x4*)(outp + 4 * u) = v;
    }
  }
  if (write_xt) {
    const int c = tid >> 2;
    const int nch = (tid & 3) * 16;
    unsigned short* __restrict__ xtp = XTout + (size_t)c * 1024 + rowbase + nch;
    s16x8 s0, s1;
#pragma unroll
    for (int j = 0; j < 8; ++j) {
      s0[j] = (short)f2bf(tile[nch + j][c]);
      s1[j] = (short)f2bf(tile[nch + 8 + j][c]);
    }
    *(s16x8*)xtp = s0;
    *(s16x8*)(xtp + 8) = s1;
  }
  __syncthreads();               // smem free for next phase
}

// ---------------------------------------------------------------------------
__global__ __launch_bounds__(256, 2) void mega(
    const float* __restrict__ x, const float* __restrict__ adj,
    const float* __restrict__ emb, const float* __restrict__ wp,
    const float* __restrict__ bp, float* __restrict__ out,
    unsigned short* XT0, unsigned short* XT1, float* X1, float* X2,
    float* wpT, unsigned short* WT, unsigned* cnt) {
  __shared__ __align__(16) char smem[32768];
  const int tid = threadIdx.x;
  const int bid = blockIdx.x;

  // ---- Phase A: transpose_x (jobs 0..255) + transpose_wp (256..305) ----
  if (bid < 256) {
    const int b = bid >> 4, n0 = (bid & 15) * 64;
    unsigned short (*tl)[72] = (unsigned short(*)[72])smem;
    {
      const int c4 = (tid & 15) * 4;
#pragma unroll
      for (int i = 0; i < 4; ++i) {
        const int row = (tid >> 4) + i * 16;
        f32x4 v =
            *(const f32x4*)(x + ((size_t)(b * 1024 + n0 + row)) * 64 + c4);
        *(uint32_t*)&tl[row][c4]     = pack2(v[0], v[1]);
        *(uint32_t*)&tl[row][c4 + 2] = pack2(v[2], v[3]);
      }
    }
    __syncthreads();
    {
      const int c = tid >> 2;
      const int nch = (tid & 3) * 16;
      s16x8 s0, s1;
#pragma unroll
      for (int j = 0; j < 8; ++j) {
        s0[j] = (short)tl[nch + j][c];
        s1[j] = (short)tl[nch + 8 + j][c];
      }
      unsigned short* p = XT0 + (size_t)(b * 64 + c) * 1024 + n0 + nch;
      *(s16x8*)p = s0;
      *(s16x8*)(p + 8) = s1;
    }
  } else if (bid < 306) {
    const int jj = bid - 256;
    const int d = jj / 5, ki0 = (jj % 5) * 64;
    float (*tl)[65] = (float(*)[65])smem;
    const float* src = wp + (size_t)d * 20480;
    {
      const int o4 = (tid & 15) * 4;
#pragma unroll
      for (int i = 0; i < 4; ++i) {
        const int row = (tid >> 4) + i * 16;
        f32x4 v = *(const f32x4*)(src + (size_t)(ki0 + row) * 64 + o4);
        tl[row][o4] = v[0]; tl[row][o4 + 1] = v[1];
        tl[row][o4 + 2] = v[2]; tl[row][o4 + 3] = v[3];
      }
    }
    __syncthreads();
    {
      const int o = tid >> 2;
      const int kch = (tid & 3) * 16;
      float* dst = wpT + (size_t)d * 20480 + (size_t)o * 320 + ki0 + kch;
#pragma unroll
      for (int u = 0; u < 4; ++u) {
        f32x4 v = { tl[kch + 4 * u][o], tl[kch + 4 * u + 1][o],
                    tl[kch + 4 * u + 2][o], tl[kch + 4 * u + 3][o] };
        *(f32x4*)(dst + 4 * u) = v;
      }
    }
  }
  gridbar(cnt, 512);

  // ---- Phase B: hop1 ----
  {
    const int bx = bid & 15, slice = bid >> 4, b = slice & 15;
    hop_body(smem, adj + (size_t)slice * 1048576,
             XT0 + (size_t)b * 65536, X1 + (size_t)slice * 65536,
             XT1 + (size_t)slice * 65536, 1, bx * 64);
  }
  gridbar(cnt, 1024);

  // ---- Phase C: hop2 (reversed for LLC locality) + wgen ----
  {
    const int job = 511 - bid;
    const int bx = job & 15, slice = job >> 4;
    hop_body(smem, adj + (size_t)slice * 1048576,
             XT1 + (size_t)slice * 65536, X2 + (size_t)slice * 65536,
             (unsigned short*)0, 0, bx * 64);
    for (int j = bid; j < 2560; j += 512) {
      const int jx = j % 40;
      const int n0 = (j / 40) * 16;
      const int idx = (jx * 256 + tid) * 2;
      f32x2 wv[10];
#pragma unroll
      for (int d = 0; d < 10; ++d)
        wv[d] = *(const f32x2*)(wpT + (size_t)d * 20480 + idx);
#pragma unroll
      for (int g = 0; g < 16; ++g) {
        float a0 = 0.f, a1 = 0.f;
#pragma unroll
        for (int d = 0; d < 10; ++d) {
          const float e = emb[(n0 + g) * 10 + d];
          a0 += e * wv[d][0];
          a1 += e * wv[d][1];
        }
        *(uint32_t*)(WT + (size_t)(n0 + g) * 20480 + idx) = pack2(a0, a1);
      }
    }
  }
  gridbar(cnt, 1536);

  // ---- Phase D: final ----
  {
    unsigned short (*xg)[16][328] = (unsigned short(*)[16][328])smem;
    const int node_base = bid * 2;
    for (int u = tid; u < 5120; u += 256) {       // units of 2 ki
      const int nd = u / 2560;
      int rem = u - nd * 2560;
      const int bb = rem / 160;
      const int kiu = rem - bb * 160;
      const int ki = kiu * 2;
      const int k = ki >> 6;
      const int c = ki & 63;
      const int nn = node_base + nd;
      const float* src;
      if (k == 0) {
        src = x + ((size_t)bb * 1024 + nn) * 64 + c;
      } else {
        const float* arr = (k == 1 || k == 3) ? X1 : X2;
        const int s = (k >= 3) ? 1 : 0;
        src = arr + ((size_t)(s * 16 + bb) * 1024 + nn) * 64 + c;
      }
      f32x2 v = *(const f32x2*)src;
      *(uint32_t*)&xg[nd][bb][ki] = pack2(v[0], v[1]);
    }
    __syncthreads();

    const int wave = tid >> 6, lane = tid & 63;
    const int nd = wave >> 1, oh = wave & 1;
    const int l15 = lane & 15, q = lane >> 4;
    const int n = node_base + nd;
    f32x4 acc[2];
#pragma unroll
    for (int t = 0; t < 2; ++t) acc[t] = (f32x4){0.f, 0.f, 0.f, 0.f};

    const unsigned short* wt0 =
        WT + (size_t)n * 20480 + (size_t)l15 * 320 + q * 8;
#pragma unroll
    for (int ks = 0; ks < 10; ++ks) {
      const int k0 = ks * 32;
      FragU af;
      af.s = *(const s16x8*)&xg[nd][l15][k0 + q * 8];
#pragma unroll
      for (int tt = 0; tt < 2; ++tt) {
        const int t = oh * 2 + tt;
        FragU bf;
        bf.s = *(const s16x8*)(wt0 + (size_t)t * (16 * 320) + k0);
        acc[tt] = __builtin_amdgcn_mfma_f32_16x16x32_bf16(af.b, bf.b, acc[tt],
                                                          0, 0, 0);
      }
    }

#pragma unroll
    for (int tt = 0; tt < 2; ++tt) {
      const int o = (oh * 2 + tt) * 16 + l15;
      float bv = 0.f;
#pragma unroll
      for (int d = 0; d < 10; ++d)
        bv += emb[n * 10 + d] * bp[d * 64 + o];
#pragma unroll
      for (int rr = 0; rr < 4; ++rr) {
        const int bb = q * 4 + rr;
        out[((size_t)bb * 1024 + n) * 64 + o] = acc[tt][rr] + bv;
      }
    }
  }
}

// ---------------------------------------------------------------------------
extern "C" void kernel_launch(void* const* d_in, const int* in_sizes, int n_in,
                              void* d_out, int out_size, void* d_ws,
                              size_t ws_size, hipStream_t stream) {
  const float* x   = (const float*)d_in[0];   // [16,1024,64]
  const float* adj = (const float*)d_in[1];   // [2,16,1024,1024]
  const float* emb = (const float*)d_in[2];   // [1024,10]
  const float* wp  = (const float*)d_in[3];   // [10,5,64,64]
  const float* bp  = (const float*)d_in[4];   // [10,64]
  float* out = (float*)d_out;                 // [16,1024,64]

  char* ws = (char*)d_ws;
  unsigned short* XT0 = (unsigned short*)(ws);                     // 2 MB
  unsigned short* XT1 = (unsigned short*)(ws + ((size_t)2 << 20)); // 4 MB
  float* X1  = (float*)(ws + ((size_t)6 << 20));                   // 8 MB
  float* X2  = (float*)(ws + ((size_t)14 << 20));                  // 8 MB
  float* wpT = (float*)(ws + ((size_t)22 << 20));                  // 0.82 MB
  unsigned short* WT = (unsigned short*)(ws + ((size_t)23 << 20)); // 40 MB
  unsigned* cnt = (unsigned*)(ws + ((size_t)64 << 20));            // barrier

  hipMemsetAsync((void*)cnt, 0, 256, stream);
  mega<<<dim3(512), dim3(256), 0, stream>>>(x, adj, emb, wp, bp, out, XT0,
                                            XT1, X1, X2, wpT, WT, cnt);
}

// Round 5
// 278.601 us; speedup vs baseline: 2.4398x; 2.4398x over previous
//
#include <hip/hip_runtime.h>
#include <stdint.h>

// ---------------------------------------------------------------------------
// PDG2Seq_GCN: B=16, N=1024, C=O=64, D=10, CHEB_K=2 (K=5 stacked terms)
// Round 5: back to stream-ordered multi-kernel (R4 grid barriers cost ~350us
// in fences/atomics). 4 launches:
//   K1 prep  (306 blk): transpose_x -> XT0 bf16; transpose_wp -> wpT
//   K2 hop1  (512 blk): X1 = A @ x (MFMA, vmcnt pipeline, 3-deep) + XT1,
//                       then each block does 5 wgen jobs (WT, no sync needed)
//   K3 hop2  (512 blk, reversed order for LLC-hot adj): X2 = A @ X1
//   K4 final (512 blk): out = Xg[16x320] @ W_n[320x64] + bias
// ---------------------------------------------------------------------------

typedef __attribute__((ext_vector_type(4))) float f32x4;
typedef __attribute__((ext_vector_type(2))) float f32x2;
typedef __attribute__((ext_vector_type(8))) short s16x8;
typedef __attribute__((ext_vector_type(8))) __bf16 bf16x8;

__device__ __forceinline__ unsigned short f2bf(float f) {
  union { float f; uint32_t u; } v; v.f = f;
  uint32_t r = v.u + 0x7FFFu + ((v.u >> 16) & 1u);   // RNE
  return (unsigned short)(r >> 16);
}
__device__ __forceinline__ uint32_t pack2(float a, float b) {
  return (uint32_t)f2bf(a) | ((uint32_t)f2bf(b) << 16);
}

union FragU { s16x8 s; bf16x8 b; };

__device__ __forceinline__ void async_cp16(const void* g, void* l) {
  __builtin_amdgcn_global_load_lds(
      (const __attribute__((address_space(1))) void*)g,
      (__attribute__((address_space(3))) void*)l, 16, 0, 0);
}

// s_waitcnt with only vmcnt constrained (expcnt=7, lgkmcnt=15 -> no wait)
#define WAITVM(n)                                                         \
  __builtin_amdgcn_s_waitcnt(((n) & 15) | ((((n) >> 4) & 3) << 14) |      \
                             (7 << 4) | (15 << 8))

// ---------------------------------------------------------------------------
// K1 prep: blocks 0..255 transpose x; 256..305 transpose wp.
// ---------------------------------------------------------------------------
__global__ __launch_bounds__(256) void prep(const float* __restrict__ x,
                                            const float* __restrict__ wp,
                                            unsigned short* __restrict__ XT0,
                                            float* __restrict__ wpT) {
  __shared__ __align__(16) char smem[17160];
  const int tid = threadIdx.x;
  const int bid = blockIdx.x;
  if (bid < 256) {
    unsigned short (*tl)[72] = (unsigned short(*)[72])smem;
    const int b = bid >> 4, n0 = (bid & 15) * 64;
    {
      const int c4 = (tid & 15) * 4;
#pragma unroll
      for (int i = 0; i < 4; ++i) {
        const int row = (tid >> 4) + i * 16;
        f32x4 v =
            *(const f32x4*)(x + ((size_t)(b * 1024 + n0 + row)) * 64 + c4);
        *(uint32_t*)&tl[row][c4]     = pack2(v[0], v[1]);
        *(uint32_t*)&tl[row][c4 + 2] = pack2(v[2], v[3]);
      }
    }
    __syncthreads();
    {
      const int c = tid >> 2;
      const int nch = (tid & 3) * 16;
      s16x8 s0, s1;
#pragma unroll
      for (int j = 0; j < 8; ++j) {
        s0[j] = (short)tl[nch + j][c];
        s1[j] = (short)tl[nch + 8 + j][c];
      }
      unsigned short* p = XT0 + (size_t)(b * 64 + c) * 1024 + n0 + nch;
      *(s16x8*)p = s0;
      *(s16x8*)(p + 8) = s1;
    }
  } else {
    float (*tl)[65] = (float(*)[65])smem;
    const int jj = bid - 256;
    const int d = jj / 5, ki0 = (jj % 5) * 64;
    const float* src = wp + (size_t)d * 20480;
    {
      const int o4 = (tid & 15) * 4;
#pragma unroll
      for (int i = 0; i < 4; ++i) {
        const int row = (tid >> 4) + i * 16;
        f32x4 v = *(const f32x4*)(src + (size_t)(ki0 + row) * 64 + o4);
        tl[row][o4] = v[0]; tl[row][o4 + 1] = v[1];
        tl[row][o4 + 2] = v[2]; tl[row][o4 + 3] = v[3];
      }
    }
    __syncthreads();
    {
      const int o = tid >> 2;
      const int kch = (tid & 3) * 16;
      float* dst = wpT + (size_t)d * 20480 + (size_t)o * 320 + ki0 + kch;
#pragma unroll
      for (int u = 0; u < 4; ++u) {
        f32x4 v = { tl[kch + 4 * u][o], tl[kch + 4 * u + 1][o],
                    tl[kch + 4 * u + 2][o], tl[kch + 4 * u + 3][o] };
        *(f32x4*)(dst + 4 * u) = v;
      }
    }
  }
}

// ---------------------------------------------------------------------------
// hop body: one 64-row tile of out = A[1024x1024] @ X[1024x64], MFMA bf16.
// Wave-private LDS A staging (3 stages x 4KB/wave), per-wave vmcnt sync,
// no block barrier in the K-loop. 12 vm ops/stage -> WAITVM(24) steady-state.
// ---------------------------------------------------------------------------
__device__ __forceinline__ void hop_body(
    char* smem, const float* __restrict__ A,
    const unsigned short* __restrict__ XT, float* __restrict__ Xout,
    unsigned short* __restrict__ XTout, int write_xt, int rowbase) {
  const int tid = threadIdx.x;
  const int wave = tid >> 6, lane = tid & 63;
  const int l15 = lane & 15, q = lane >> 4;

  float* const Abase = (float*)smem + wave * 3072;   // 3 stages x 1024 f32

  const float* ag[4];
#pragma unroll
  for (int i = 0; i < 4; ++i) {
    const int wl = i * 4 + (lane >> 4);              // wave-local row 0..15
    const int ch = (lane & 15) ^ (wl & 7);           // swizzled 4-float chunk
    ag[i] = A + (size_t)(rowbase + wave * 16 + wl) * 1024 + ch * 4;
  }
  const unsigned short* bg[8];
#pragma unroll
  for (int t = 0; t < 4; ++t)
#pragma unroll
    for (int h = 0; h < 2; ++h)
      bg[t * 2 + h] = XT + (size_t)(t * 16 + l15) * 1024 + h * 32 + q * 8;

  f32x4 acc[4];
#pragma unroll
  for (int t = 0; t < 4; ++t) acc[t] = (f32x4){0.f, 0.f, 0.f, 0.f};

  s16x8 breg0[8], breg1[8], breg2[8];

  auto issueA = [&](int k0, int s) {
#pragma unroll
    for (int i = 0; i < 4; ++i)
      async_cp16(ag[i] + k0, Abase + s * 1024 + i * 256);
  };
  auto issueB = [&](int k0, s16x8 (&br)[8]) {
#pragma unroll
    for (int j = 0; j < 8; ++j) br[j] = *(const s16x8*)(bg[j] + k0);
  };
  auto compute = [&](int s, const s16x8 (&br)[8]) {
    const float* Ab = Abase + s * 1024;
    const int sw = l15 & 7;
#pragma unroll
    for (int h = 0; h < 2; ++h) {
      const int j0 = h * 8 + q * 2;
      f32x4 c0 = *(const f32x4*)(Ab + l15 * 64 + (j0 ^ sw) * 4);
      f32x4 c1 = *(const f32x4*)(Ab + l15 * 64 + ((j0 + 1) ^ sw) * 4);
      FragU af;
#pragma unroll
      for (int e = 0; e < 4; ++e) {
        af.s[e]     = (short)f2bf(c0[e]);
        af.s[e + 4] = (short)f2bf(c1[e]);
      }
#pragma unroll
      for (int t = 0; t < 4; ++t) {
        FragU bf; bf.s = br[t * 2 + h];
        acc[t] = __builtin_amdgcn_mfma_f32_16x16x32_bf16(af.b, bf.b, acc[t],
                                                         0, 0, 0);
      }
    }
  };

  issueA(0, 0);     issueB(0, breg0);
  issueA(64, 1);    issueB(64, breg1);
  issueA(128, 2);   issueB(128, breg2);
#pragma unroll 1
  for (int kt = 0; kt < 12; kt += 3) {
    WAITVM(24);
    compute(0, breg0);
    issueA((kt + 3) * 64, 0); issueB((kt + 3) * 64, breg0);
    WAITVM(24);
    compute(1, breg1);
    issueA((kt + 4) * 64, 1); issueB((kt + 4) * 64, breg1);
    WAITVM(24);
    compute(2, breg2);
    issueA((kt + 5) * 64, 2); issueB((kt + 5) * 64, breg2);
  }
  WAITVM(24);
  compute(0, breg0);                      // stage 12
  issueA(960, 0); issueB(960, breg0);     // stage 15 -> slot 0
  WAITVM(24);
  compute(1, breg1);                      // stage 13
  WAITVM(12);
  compute(2, breg2);                      // stage 14
  WAITVM(0);
  compute(0, breg0);                      // stage 15

  // Epilogue: transpose via LDS (reuse stage memory)
  __syncthreads();
  float (*tile)[65] = (float(*)[65])smem;
#pragma unroll
  for (int t = 0; t < 4; ++t)
#pragma unroll
    for (int rr = 0; rr < 4; ++rr)
      tile[wave * 16 + q * 4 + rr][t * 16 + l15] = acc[t][rr];
  __syncthreads();

  {
    const int row = tid >> 2;
    const int cb = (tid & 3) * 16;
    float* __restrict__ outp = Xout + (size_t)(rowbase + row) * 64 + cb;
#pragma unroll
    for (int u = 0; u < 4; ++u) {
      f32x4 v = { tile[row][cb + 4 * u], tile[row][cb + 4 * u + 1],
                  tile[row][cb + 4 * u + 2], tile[row][cb + 4 * u + 3] };
      *(f32x4*)(outp + 4 * u) = v;
    }
  }
  if (write_xt) {
    const int c = tid >> 2;
    const int nch = (tid & 3) * 16;
    unsigned short* __restrict__ xtp = XTout + (size_t)c * 1024 + rowbase + nch;
    s16x8 s0, s1;
#pragma unroll
    for (int j = 0; j < 8; ++j) {
      s0[j] = (short)f2bf(tile[nch + j][c]);
      s1[j] = (short)f2bf(tile[nch + 8 + j][c]);
    }
    *(s16x8*)xtp = s0;
    *(s16x8*)(xtp + 8) = s1;
  }
}

// ---------------------------------------------------------------------------
// K2 hop1 + wgen tail. grid (16 row-tiles, 32 slices).
// ---------------------------------------------------------------------------
__global__ __launch_bounds__(256, 2) void hop1_kernel(
    const float* __restrict__ adj, const unsigned short* __restrict__ XT0,
    float* __restrict__ X1, unsigned short* __restrict__ XT1,
    const float* __restrict__ wpT, const float* __restrict__ emb,
    unsigned short* __restrict__ WT) {
  __shared__ __align__(16) char smem[49152];
  const int bx = blockIdx.x, slice = blockIdx.y, b = slice & 15;
  hop_body(smem, adj + (size_t)slice * 1048576, XT0 + (size_t)b * 65536,
           X1 + (size_t)slice * 65536, XT1 + (size_t)slice * 65536, 1,
           bx * 64);

  // wgen: 2560 jobs over 512 blocks -> 5 each. WT[n][o][ki] bf16.
  const int bid = slice * 16 + bx;
  const int tid = threadIdx.x;
#pragma unroll 1
  for (int j = bid * 5; j < bid * 5 + 5; ++j) {
    const int jx = j % 40;
    const int n0 = (j / 40) * 16;
    const int idx = (jx * 256 + tid) * 2;
    f32x2 wv[10];
#pragma unroll
    for (int d = 0; d < 10; ++d)
      wv[d] = *(const f32x2*)(wpT + (size_t)d * 20480 + idx);
#pragma unroll
    for (int g = 0; g < 16; ++g) {
      float a0 = 0.f, a1 = 0.f;
#pragma unroll
      for (int d = 0; d < 10; ++d) {
        const float e = emb[(n0 + g) * 10 + d];
        a0 += e * wv[d][0];
        a1 += e * wv[d][1];
      }
      *(uint32_t*)(WT + (size_t)(n0 + g) * 20480 + idx) = pack2(a0, a1);
    }
  }
}

// ---------------------------------------------------------------------------
// K3 hop2, reversed block order (consume hop1's LLC-resident adj tail first).
// ---------------------------------------------------------------------------
__global__ __launch_bounds__(256, 2) void hop2_kernel(
    const float* __restrict__ adj, const unsigned short* __restrict__ XT1,
    float* __restrict__ X2) {
  __shared__ __align__(16) char smem[49152];
  const int bx = 15 - (int)blockIdx.x;
  const int slice = 31 - (int)blockIdx.y;
  hop_body(smem, adj + (size_t)slice * 1048576, XT1 + (size_t)slice * 65536,
           X2 + (size_t)slice * 65536, (unsigned short*)0, 0, bx * 64);
}

// ---------------------------------------------------------------------------
// K4 final: out[b,n,o] = Xg[b,n,:] (320) @ W_n[320,64] + bias[n,o]
// 2 nodes/block, 2 waves per node. grid 512, block 256.
// ---------------------------------------------------------------------------
__global__ __launch_bounds__(256, 2) void final_kernel(
    const float* __restrict__ x, const float* __restrict__ X1,
    const float* __restrict__ X2, const unsigned short* __restrict__ WT,
    const float* __restrict__ emb, const float* __restrict__ bias_pool,
    float* __restrict__ out) {
  __shared__ unsigned short xg[2][16][328];
  const int tid = threadIdx.x;
  const int node_base = blockIdx.x * 2;

  for (int u = tid; u < 5120; u += 256) {       // units of 2 ki
    const int nd = u / 2560;
    int rem = u - nd * 2560;
    const int bb = rem / 160;
    const int kiu = rem - bb * 160;
    const int ki = kiu * 2;
    const int k = ki >> 6;
    const int c = ki & 63;
    const int nn = node_base + nd;
    const float* src;
    if (k == 0) {
      src = x + ((size_t)bb * 1024 + nn) * 64 + c;
    } else {
      const float* arr = (k == 1 || k == 3) ? X1 : X2;
      const int s = (k >= 3) ? 1 : 0;
      src = arr + ((size_t)(s * 16 + bb) * 1024 + nn) * 64 + c;
    }
    f32x2 v = *(const f32x2*)src;
    *(uint32_t*)&xg[nd][bb][ki] = pack2(v[0], v[1]);
  }
  __syncthreads();

  const int wave = tid >> 6, lane = tid & 63;
  const int nd = wave >> 1, oh = wave & 1;
  const int l15 = lane & 15, q = lane >> 4;
  const int n = node_base + nd;
  f32x4 acc[2];
#pragma unroll
  for (int t = 0; t < 2; ++t) acc[t] = (f32x4){0.f, 0.f, 0.f, 0.f};

  const unsigned short* wt0 =
      WT + (size_t)n * 20480 + (size_t)l15 * 320 + q * 8;
#pragma unroll
  for (int ks = 0; ks < 10; ++ks) {
    const int k0 = ks * 32;
    FragU af;
    af.s = *(const s16x8*)&xg[nd][l15][k0 + q * 8];
#pragma unroll
    for (int tt = 0; tt < 2; ++tt) {
      const int t = oh * 2 + tt;
      FragU bf;
      bf.s = *(const s16x8*)(wt0 + (size_t)t * (16 * 320) + k0);
      acc[tt] = __builtin_amdgcn_mfma_f32_16x16x32_bf16(af.b, bf.b, acc[tt],
                                                        0, 0, 0);
    }
  }

#pragma unroll
  for (int tt = 0; tt < 2; ++tt) {
    const int o = (oh * 2 + tt) * 16 + l15;
    float bv = 0.f;
#pragma unroll
    for (int d = 0; d < 10; ++d)
      bv += emb[n * 10 + d] * bias_pool[d * 64 + o];
#pragma unroll
    for (int rr = 0; rr < 4; ++rr) {
      const int bb = q * 4 + rr;
      out[((size_t)bb * 1024 + n) * 64 + o] = acc[tt][rr] + bv;
    }
  }
}

// ---------------------------------------------------------------------------
extern "C" void kernel_launch(void* const* d_in, const int* in_sizes, int n_in,
                              void* d_out, int out_size, void* d_ws,
                              size_t ws_size, hipStream_t stream) {
  const float* x   = (const float*)d_in[0];   // [16,1024,64]
  const float* adj = (const float*)d_in[1];   // [2,16,1024,1024]
  const float* emb = (const float*)d_in[2];   // [1024,10]
  const float* wp  = (const float*)d_in[3];   // [10,5,64,64]
  const float* bp  = (const float*)d_in[4];   // [10,64]
  float* out = (float*)d_out;                 // [16,1024,64]

  char* ws = (char*)d_ws;
  unsigned short* XT0 = (unsigned short*)(ws);                     // 2 MB
  unsigned short* XT1 = (unsigned short*)(ws + ((size_t)2 << 20)); // 4 MB
  float* X1  = (float*)(ws + ((size_t)6 << 20));                   // 8 MB
  float* X2  = (float*)(ws + ((size_t)14 << 20));                  // 8 MB
  float* wpT = (float*)(ws + ((size_t)22 << 20));                  // 0.82 MB
  unsigned short* WT = (unsigned short*)(ws + ((size_t)23 << 20)); // 40 MB

  prep<<<dim3(306), dim3(256), 0, stream>>>(x, wp, XT0, wpT);
  hop1_kernel<<<dim3(16, 32), dim3(256), 0, stream>>>(adj, XT0, X1, XT1,
                                                      wpT, emb, WT);
  hop2_kernel<<<dim3(16, 32), dim3(256), 0, stream>>>(adj, XT1, X2);
  final_kernel<<<dim3(512), dim3(256), 0, stream>>>(x, X1, X2, WT, emb, bp,
                                                    out);
}

// Round 6
// 271.102 us; speedup vs baseline: 2.5073x; 1.0277x over previous
//
#include <hip/hip_runtime.h>
#include <stdint.h>

// ---------------------------------------------------------------------------
// PDG2Seq_GCN: B=16, N=1024, C=O=64, D=10, CHEB_K=2 (K=5 stacked terms)
// Round 6: pre-convert adj fp32 -> bf16 (67 MB, LLC-resident, serves both
// hops); hop K-loop is lean m97-style: A and B both bf16 staged to LDS via
// global_load_lds (4 DMA instrs/stage/wave, zero data VGPRs, no f2bf in
// loop), 32 KB double-buffered LDS, 1 barrier/stage.
// Launches: cvt_adj, prep, hop1(+wgen tail), hop2, final.
// ---------------------------------------------------------------------------

typedef __attribute__((ext_vector_type(4))) float f32x4;
typedef __attribute__((ext_vector_type(2))) float f32x2;
typedef __attribute__((ext_vector_type(8))) short s16x8;
typedef __attribute__((ext_vector_type(8))) __bf16 bf16x8;

__device__ __forceinline__ unsigned short f2bf(float f) {
  union { float f; uint32_t u; } v; v.f = f;
  uint32_t r = v.u + 0x7FFFu + ((v.u >> 16) & 1u);   // RNE
  return (unsigned short)(r >> 16);
}
__device__ __forceinline__ uint32_t pack2(float a, float b) {
  return (uint32_t)f2bf(a) | ((uint32_t)f2bf(b) << 16);
}

union FragU { s16x8 s; bf16x8 b; };

__device__ __forceinline__ void async_cp16(const void* g, void* l) {
  __builtin_amdgcn_global_load_lds(
      (const __attribute__((address_space(1))) void*)g,
      (__attribute__((address_space(3))) void*)l, 16, 0, 0);
}

// ---------------------------------------------------------------------------
// K0 cvt_adj: adj f32 [33554432] -> adjb bf16. Streaming, grid-stride.
// ---------------------------------------------------------------------------
__global__ __launch_bounds__(256) void cvt_adj(const float* __restrict__ adj,
                                               unsigned short* __restrict__ adjb) {
  const size_t stride = (size_t)gridDim.x * 256 * 8;
  for (size_t p = ((size_t)blockIdx.x * 256 + threadIdx.x) * 8;
       p < 33554432u; p += stride) {
    f32x4 a = *(const f32x4*)(adj + p);
    f32x4 b = *(const f32x4*)(adj + p + 4);
    union { s16x8 s; uint32_t u[4]; } o;
    o.u[0] = pack2(a[0], a[1]);
    o.u[1] = pack2(a[2], a[3]);
    o.u[2] = pack2(b[0], b[1]);
    o.u[3] = pack2(b[2], b[3]);
    *(s16x8*)(adjb + p) = o.s;
  }
}

// ---------------------------------------------------------------------------
// K1 prep: blocks 0..255 transpose x -> XT0 bf16; 256..305 transpose wp.
// ---------------------------------------------------------------------------
__global__ __launch_bounds__(256) void prep(const float* __restrict__ x,
                                            const float* __restrict__ wp,
                                            unsigned short* __restrict__ XT0,
                                            float* __restrict__ wpT) {
  __shared__ __align__(16) char smem[17160];
  const int tid = threadIdx.x;
  const int bid = blockIdx.x;
  if (bid < 256) {
    unsigned short (*tl)[72] = (unsigned short(*)[72])smem;
    const int b = bid >> 4, n0 = (bid & 15) * 64;
    {
      const int c4 = (tid & 15) * 4;
#pragma unroll
      for (int i = 0; i < 4; ++i) {
        const int row = (tid >> 4) + i * 16;
        f32x4 v =
            *(const f32x4*)(x + ((size_t)(b * 1024 + n0 + row)) * 64 + c4);
        *(uint32_t*)&tl[row][c4]     = pack2(v[0], v[1]);
        *(uint32_t*)&tl[row][c4 + 2] = pack2(v[2], v[3]);
      }
    }
    __syncthreads();
    {
      const int c = tid >> 2;
      const int nch = (tid & 3) * 16;
      s16x8 s0, s1;
#pragma unroll
      for (int j = 0; j < 8; ++j) {
        s0[j] = (short)tl[nch + j][c];
        s1[j] = (short)tl[nch + 8 + j][c];
      }
      unsigned short* p = XT0 + (size_t)(b * 64 + c) * 1024 + n0 + nch;
      *(s16x8*)p = s0;
      *(s16x8*)(p + 8) = s1;
    }
  } else {
    float (*tl)[65] = (float(*)[65])smem;
    const int jj = bid - 256;
    const int d = jj / 5, ki0 = (jj % 5) * 64;
    const float* src = wp + (size_t)d * 20480;
    {
      const int o4 = (tid & 15) * 4;
#pragma unroll
      for (int i = 0; i < 4; ++i) {
        const int row = (tid >> 4) + i * 16;
        f32x4 v = *(const f32x4*)(src + (size_t)(ki0 + row) * 64 + o4);
        tl[row][o4] = v[0]; tl[row][o4 + 1] = v[1];
        tl[row][o4 + 2] = v[2]; tl[row][o4 + 3] = v[3];
      }
    }
    __syncthreads();
    {
      const int o = tid >> 2;
      const int kch = (tid & 3) * 16;
      float* dst = wpT + (size_t)d * 20480 + (size_t)o * 320 + ki0 + kch;
#pragma unroll
      for (int u = 0; u < 4; ++u) {
        f32x4 v = { tl[kch + 4 * u][o], tl[kch + 4 * u + 1][o],
                    tl[kch + 4 * u + 2][o], tl[kch + 4 * u + 3][o] };
        *(f32x4*)(dst + 4 * u) = v;
      }
    }
  }
}

// ---------------------------------------------------------------------------
// hop body: out[64 rows][64] = A[1024x1024]bf16 @ X[1024x64], MFMA bf16.
// Stage (A 8KB + B 8KB) double-buffered in LDS via global_load_lds;
// 4 DMA instrs/stage/wave; 1 __syncthreads per stage. Chunk-XOR swizzle
// (ch ^ (row&7)) applied on the GLOBAL source so LDS frag reads are
// bank-balanced. A and B are both [row][1024] bf16 layouts.
// ---------------------------------------------------------------------------
__device__ __forceinline__ void hop_body(
    char* smem, const unsigned short* __restrict__ A,
    const unsigned short* __restrict__ XT, float* __restrict__ Xout,
    unsigned short* __restrict__ XTout, int write_xt, int rowbase) {
  const int tid = threadIdx.x;
  const int wave = tid >> 6, lane = tid & 63;
  const int l15 = lane & 15, q = lane >> 4;

  unsigned short* const Ast = (unsigned short*)smem;          // [2][64][64]
  unsigned short* const Bst = (unsigned short*)smem + 8192;   // [2][64][64]

  const int sub = lane >> 3;            // row-in-8
  const int ch = lane & 7;              // 8-short chunk
  const unsigned short* asrc[2];
  const unsigned short* bsrc[2];
  int ldso[2];
#pragma unroll
  for (int i = 0; i < 2; ++i) {
    const int r = wave * 16 + i * 8 + sub;
    asrc[i] = A + (size_t)(rowbase + r) * 1024 + (ch ^ (r & 7)) * 8;
    bsrc[i] = XT + (size_t)r * 1024 + (ch ^ (r & 7)) * 8;
    ldso[i] = (wave * 16 + i * 8) * 64;
  }

  f32x4 acc[4];
#pragma unroll
  for (int t = 0; t < 4; ++t) acc[t] = (f32x4){0.f, 0.f, 0.f, 0.f};

  auto issue = [&](int s, int k0) {
#pragma unroll
    for (int i = 0; i < 2; ++i) {
      async_cp16(asrc[i] + k0, Ast + s * 4096 + ldso[i]);
      async_cp16(bsrc[i] + k0, Bst + s * 4096 + ldso[i]);
    }
  };
  const int sw = l15 & 7;
  auto compute = [&](int s) {
    const unsigned short* Ab = Ast + s * 4096 + (wave * 16 + l15) * 64;
    const unsigned short* Bb = Bst + s * 4096 + l15 * 64;
#pragma unroll
    for (int h = 0; h < 2; ++h) {
      const int cko = ((h * 4 + q) ^ sw) * 8;
      FragU af;
      af.s = *(const s16x8*)(Ab + cko);
#pragma unroll
      for (int t = 0; t < 4; ++t) {
        FragU bf;
        bf.s = *(const s16x8*)(Bb + t * 1024 + cko);
        acc[t] = __builtin_amdgcn_mfma_f32_16x16x32_bf16(af.b, bf.b, acc[t],
                                                         0, 0, 0);
      }
    }
  };

  issue(0, 0);
#pragma unroll 1
  for (int kt = 0; kt < 16; ++kt) {
    const int cur = kt & 1;
    __syncthreads();                   // stage kt landed (vmcnt drain)
    if (kt + 1 < 16) issue(cur ^ 1, (kt + 1) * 64);
    compute(cur);
  }

  // Epilogue: transpose via LDS (reuse stage memory)
  __syncthreads();
  float (*tile)[65] = (float(*)[65])smem;
#pragma unroll
  for (int t = 0; t < 4; ++t)
#pragma unroll
    for (int rr = 0; rr < 4; ++rr)
      tile[wave * 16 + q * 4 + rr][t * 16 + l15] = acc[t][rr];
  __syncthreads();

  {
    const int row = tid >> 2;
    const int cb = (tid & 3) * 16;
    float* __restrict__ outp = Xout + (size_t)(rowbase + row) * 64 + cb;
#pragma unroll
    for (int u = 0; u < 4; ++u) {
      f32x4 v = { tile[row][cb + 4 * u], tile[row][cb + 4 * u + 1],
                  tile[row][cb + 4 * u + 2], tile[row][cb + 4 * u + 3] };
      *(f32x4*)(outp + 4 * u) = v;
    }
  }
  if (write_xt) {
    const int c = tid >> 2;
    const int nch = (tid & 3) * 16;
    unsigned short* __restrict__ xtp = XTout + (size_t)c * 1024 + rowbase + nch;
    s16x8 s0, s1;
#pragma unroll
    for (int j = 0; j < 8; ++j) {
      s0[j] = (short)f2bf(tile[nch + j][c]);
      s1[j] = (short)f2bf(tile[nch + 8 + j][c]);
    }
    *(s16x8*)xtp = s0;
    *(s16x8*)(xtp + 8) = s1;
  }
}

// ---------------------------------------------------------------------------
// K2 hop1 + wgen tail. grid (16 row-tiles, 32 slices).
// ---------------------------------------------------------------------------
__global__ __launch_bounds__(256, 4) void hop1_kernel(
    const unsigned short* __restrict__ adjb,
    const unsigned short* __restrict__ XT0, float* __restrict__ X1,
    unsigned short* __restrict__ XT1, const float* __restrict__ wpT,
    const float* __restrict__ emb, unsigned short* __restrict__ WT) {
  __shared__ __align__(16) char smem[32768];
  const int bx = blockIdx.x, slice = blockIdx.y, b = slice & 15;
  hop_body(smem, adjb + (size_t)slice * 1048576, XT0 + (size_t)b * 65536,
           X1 + (size_t)slice * 65536, XT1 + (size_t)slice * 65536, 1,
           bx * 64);

  // wgen: 2560 jobs over 512 blocks -> 5 each. WT[n][o][ki] bf16.
  const int bid = slice * 16 + bx;
  const int tid = threadIdx.x;
#pragma unroll 1
  for (int j = bid * 5; j < bid * 5 + 5; ++j) {
    const int jx = j % 40;
    const int n0 = (j / 40) * 16;
    const int idx = (jx * 256 + tid) * 2;
    f32x2 wv[10];
#pragma unroll
    for (int d = 0; d < 10; ++d)
      wv[d] = *(const f32x2*)(wpT + (size_t)d * 20480 + idx);
#pragma unroll
    for (int g = 0; g < 16; ++g) {
      float a0 = 0.f, a1 = 0.f;
#pragma unroll
      for (int d = 0; d < 10; ++d) {
        const float e = emb[(n0 + g) * 10 + d];
        a0 += e * wv[d][0];
        a1 += e * wv[d][1];
      }
      *(uint32_t*)(WT + (size_t)(n0 + g) * 20480 + idx) = pack2(a0, a1);
    }
  }
}

// ---------------------------------------------------------------------------
// K3 hop2, reversed block order (LLC-hot adjb tail first).
// ---------------------------------------------------------------------------
__global__ __launch_bounds__(256, 4) void hop2_kernel(
    const unsigned short* __restrict__ adjb,
    const unsigned short* __restrict__ XT1, float* __restrict__ X2) {
  __shared__ __align__(16) char smem[32768];
  const int bx = 15 - (int)blockIdx.x;
  const int slice = 31 - (int)blockIdx.y;
  hop_body(smem, adjb + (size_t)slice * 1048576, XT1 + (size_t)slice * 65536,
           X2 + (size_t)slice * 65536, (unsigned short*)0, 0, bx * 64);
}

// ---------------------------------------------------------------------------
// K4 final: out[b,n,o] = Xg[b,n,:] (320) @ W_n[320,64] + bias[n,o]
// 2 nodes/block, 2 waves per node. grid 512, block 256.
// ---------------------------------------------------------------------------
__global__ __launch_bounds__(256, 2) void final_kernel(
    const float* __restrict__ x, const float* __restrict__ X1,
    const float* __restrict__ X2, const unsigned short* __restrict__ WT,
    const float* __restrict__ emb, const float* __restrict__ bias_pool,
    float* __restrict__ out) {
  __shared__ unsigned short xg[2][16][328];
  const int tid = threadIdx.x;
  const int node_base = blockIdx.x * 2;

  for (int u = tid; u < 5120; u += 256) {       // units of 2 ki
    const int nd = u / 2560;
    int rem = u - nd * 2560;
    const int bb = rem / 160;
    const int kiu = rem - bb * 160;
    const int ki = kiu * 2;
    const int k = ki >> 6;
    const int c = ki & 63;
    const int nn = node_base + nd;
    const float* src;
    if (k == 0) {
      src = x + ((size_t)bb * 1024 + nn) * 64 + c;
    } else {
      const float* arr = (k == 1 || k == 3) ? X1 : X2;
      const int s = (k >= 3) ? 1 : 0;
      src = arr + ((size_t)(s * 16 + bb) * 1024 + nn) * 64 + c;
    }
    f32x2 v = *(const f32x2*)src;
    *(uint32_t*)&xg[nd][bb][ki] = pack2(v[0], v[1]);
  }
  __syncthreads();

  const int wave = tid >> 6, lane = tid & 63;
  const int nd = wave >> 1, oh = wave & 1;
  const int l15 = lane & 15, q = lane >> 4;
  const int n = node_base + nd;
  f32x4 acc[2];
#pragma unroll
  for (int t = 0; t < 2; ++t) acc[t] = (f32x4){0.f, 0.f, 0.f, 0.f};

  const unsigned short* wt0 =
      WT + (size_t)n * 20480 + (size_t)l15 * 320 + q * 8;
#pragma unroll
  for (int ks = 0; ks < 10; ++ks) {
    const int k0 = ks * 32;
    FragU af;
    af.s = *(const s16x8*)&xg[nd][l15][k0 + q * 8];
#pragma unroll
    for (int tt = 0; tt < 2; ++tt) {
      const int t = oh * 2 + tt;
      FragU bf;
      bf.s = *(const s16x8*)(wt0 + (size_t)t * (16 * 320) + k0);
      acc[tt] = __builtin_amdgcn_mfma_f32_16x16x32_bf16(af.b, bf.b, acc[tt],
                                                        0, 0, 0);
    }
  }

#pragma unroll
  for (int tt = 0; tt < 2; ++tt) {
    const int o = (oh * 2 + tt) * 16 + l15;
    float bv = 0.f;
#pragma unroll
    for (int d = 0; d < 10; ++d)
      bv += emb[n * 10 + d] * bias_pool[d * 64 + o];
#pragma unroll
    for (int rr = 0; rr < 4; ++rr) {
      const int bb = q * 4 + rr;
      out[((size_t)bb * 1024 + n) * 64 + o] = acc[tt][rr] + bv;
    }
  }
}

// ---------------------------------------------------------------------------
extern "C" void kernel_launch(void* const* d_in, const int* in_sizes, int n_in,
                              void* d_out, int out_size, void* d_ws,
                              size_t ws_size, hipStream_t stream) {
  const float* x   = (const float*)d_in[0];   // [16,1024,64]
  const float* adj = (const float*)d_in[1];   // [2,16,1024,1024]
  const float* emb = (const float*)d_in[2];   // [1024,10]
  const float* wp  = (const float*)d_in[3];   // [10,5,64,64]
  const float* bp  = (const float*)d_in[4];   // [10,64]
  float* out = (float*)d_out;                 // [16,1024,64]

  char* ws = (char*)d_ws;
  unsigned short* XT0 = (unsigned short*)(ws);                     // 2 MB
  unsigned short* XT1 = (unsigned short*)(ws + ((size_t)2 << 20)); // 4 MB
  float* X1  = (float*)(ws + ((size_t)6 << 20));                   // 8 MB
  float* X2  = (float*)(ws + ((size_t)14 << 20));                  // 8 MB
  float* wpT = (float*)(ws + ((size_t)22 << 20));                  // 0.82 MB
  unsigned short* WT = (unsigned short*)(ws + ((size_t)23 << 20)); // 40 MB
  unsigned short* adjb = (unsigned short*)(ws + ((size_t)64 << 20)); // 67 MB

  cvt_adj<<<dim3(8192), dim3(256), 0, stream>>>(adj, adjb);
  prep<<<dim3(306), dim3(256), 0, stream>>>(x, wp, XT0, wpT);
  hop1_kernel<<<dim3(16, 32), dim3(256), 0, stream>>>(adjb, XT0, X1, XT1,
                                                      wpT, emb, WT);
  hop2_kernel<<<dim3(16, 32), dim3(256), 0, stream>>>(adjb, XT1, X2);
  final_kernel<<<dim3(512), dim3(256), 0, stream>>>(x, X1, X2, WT, emb, bp,
                                                    out);
}